// Round 11
// baseline (161.041 us; speedup 1.0000x reference)
//
#include <hip/hip_runtime.h>

#define NT 256
#define RCHUNK 32
#define NSLOT 32

typedef float f2 __attribute__((ext_vector_type(2)));
typedef float f4 __attribute__((ext_vector_type(4)));

__device__ __forceinline__ float bl32(__amdgpu_buffer_rsrc_t r, int voff) {
    return __builtin_bit_cast(float, __builtin_amdgcn_raw_buffer_load_b32(r, voff, 0, 0));
}
__device__ __forceinline__ f2 bl64(__amdgpu_buffer_rsrc_t r, int voff) {
    return __builtin_bit_cast(f2, __builtin_amdgcn_raw_buffer_load_b64(r, voff, 0, 0));
}
__device__ __forceinline__ f4 bl128(__amdgpu_buffer_rsrc_t r, int voff) {
    return __builtin_bit_cast(f4, __builtin_amdgcn_raw_buffer_load_b128(r, voff, 0, 0));
}

__device__ __forceinline__ float ccval(float sI, float sJ, float sII, float sJJ,
                                       float sIJ, float inv_ws) {
    float cross = fmaf(-(sI * sJ), inv_ws, sIJ);
    float iv    = fmaf(-(sI * sI), inv_ws, sII);
    float jv    = fmaf(-(sJ * sJ), inv_ws, sJJ);
    float den   = fmaf(iv, jv, 1e-8f);
    return (cross * cross) * __builtin_amdgcn_rcpf(den);
}

// Wave-autonomous, ZERO-LDS, ZERO-sync. Wave owns 64 cols x RCHUNK rows.
// Lane tap offsets are LOOP-INVARIANT (column fixed); per row only the
// wave-uniform SRD row base changes (SALU). Taps loaded as exact-offset wide
// buffer loads (4B-aligned b128 is legal on MUBUF; per-dword bounds check
// zero-pads edges; low-edge unsigned wrap is modularly consistent - proven in
// round 8). Vertical 5-stat sliding window in a register ring, literal slots.
template<int W, int WIN, int S>
__device__ void level_wave(const float* __restrict__ yh,
                           const float* __restrict__ y,
                           int sub, float* __restrict__ ws_acc, int level, int wid)
{
    constexpr int HW = WIN / 2;
    constexpr int T  = RCHUNK + 2 * HW;
    constexpr int G  = (T + WIN - 1) / WIN;
    constexpr int OFF = (S - 2) / 2;
    constexpr int NF4 = (WIN + 3) / 4;          // f4 loads covering WIN taps (over-read OOB->0)
    constexpr float INV_WS = 1.0f / (float)(WIN * WIN);
    constexpr int STRIPS = W / 64;
    constexpr int CHUNKS = W / RCHUNK;

    int b     = sub / (STRIPS * CHUNKS);
    int rem   = sub - b * (STRIPS * CHUNKS);
    int chunk = rem / STRIPS;
    int strip = rem - chunk * STRIPS;
    int r0 = chunk * RCHUNK;
    int c0 = strip * 64;

    const float* Jb = yh + (size_t)b * W * W;
    const float* Yb = y  + (size_t)b * 512 * 512;

    int l = threadIdx.x & 63;
    // loop-invariant per-lane byte offsets (may wrap negative -> OOB -> 0)
    int vbJ = (c0 + l - HW) * 4;
    int vbI = (S * (c0 + l - HW) + OFF) * 4;    // S>=2 only

    float rI[WIN], rJ[WIN], rII[WIN], rJJ[WIN], rIJ[WIN];
#pragma unroll
    for (int k = 0; k < WIN; ++k) { rI[k]=0.f; rJ[k]=0.f; rII[k]=0.f; rJJ[k]=0.f; rIJ[k]=0.f; }
    float vI=0.f, vJ=0.f, vII=0.f, vJJ=0.f, vIJ=0.f;
    float l2acc = 0.f, ccacc = 0.f;

    for (int g = 0; g < G; ++g) {
#pragma unroll
        for (int u = 0; u < WIN; ++u) {
            int rr = g * WIN + u;          // wave-uniform
            if (rr < T) {
                int r = r0 - HW + rr;
                bool valid = (r >= 0) && (r < W);
                int rc = valid ? r : 0;
                int nrJ = valid ? W * 4 : 0;
                int nrY = valid ? 2048 : 0;

                float qJ[WIN], qI[WIN];
                {
                    auto rsJ = __builtin_amdgcn_make_buffer_rsrc(
                        (void*)(Jb + (long)rc * W), (short)0, nrJ, 0x00020000);
                    f4 LJ[NF4];
#pragma unroll
                    for (int k = 0; k < NF4; ++k) LJ[k] = bl128(rsJ, vbJ + 16 * k);
#pragma unroll
                    for (int i = 0; i < WIN; ++i) qJ[i] = LJ[i / 4][i % 4];
                }
                if constexpr (S == 1) {
                    auto rsI = __builtin_amdgcn_make_buffer_rsrc(
                        (void*)(Yb + (long)rc * 512), (short)0, nrY, 0x00020000);
                    f4 LI[NF4];
#pragma unroll
                    for (int k = 0; k < NF4; ++k) LI[k] = bl128(rsI, vbJ + 16 * k);
#pragma unroll
                    for (int i = 0; i < WIN; ++i) qI[i] = LI[i / 4][i % 4];
                } else {
                    int yr = S * rc + OFF;
                    auto rsA = __builtin_amdgcn_make_buffer_rsrc(
                        (void*)(Yb + (long)yr * 512), (short)0, nrY, 0x00020000);
                    auto rsB = __builtin_amdgcn_make_buffer_rsrc(
                        (void*)(Yb + (long)(yr + 1) * 512), (short)0, nrY, 0x00020000);
#pragma unroll
                    for (int i = 0; i < WIN; ++i) {
                        f2 a  = bl64(rsA, vbI + 4 * S * i);
                        f2 bb = bl64(rsB, vbI + 4 * S * i);
                        qI[i] = 0.25f * ((a.x + a.y) + (bb.x + bb.y));
                    }
                }

                float sI=0.f, sJ=0.f, sII=0.f, sJJ=0.f, sIJ=0.f;
#pragma unroll
                for (int k = 0; k < WIN; ++k) {
                    sI += qI[k]; sJ += qJ[k];
                    sII = fmaf(qI[k], qI[k], sII);
                    sJJ = fmaf(qJ[k], qJ[k], sJJ);
                    sIJ = fmaf(qI[k], qJ[k], sIJ);
                }
                if (rr >= HW && rr < HW + RCHUNK) {
                    float d = qJ[HW] - qI[HW];
                    l2acc = fmaf(d, d, l2acc);
                }
                rI[u]=sI; rJ[u]=sJ; rII[u]=sII; rJJ[u]=sJJ; rIJ[u]=sIJ;
                vI+=sI; vJ+=sJ; vII+=sII; vJJ+=sJJ; vIJ+=sIJ;
                if (rr >= 2 * HW) {
                    ccacc += ccval(vI, vJ, vII, vJJ, vIJ, INV_WS);
                    const int uo = (u + 1) % WIN;   // literal after unroll
                    vI-=rI[uo]; vJ-=rJ[uo]; vII-=rII[uo]; vJJ-=rJJ[uo]; vIJ-=rIJ[uo];
                }
            }
        }
    }

#pragma unroll
    for (int off = 32; off > 0; off >>= 1) {
        l2acc += __shfl_down(l2acc, off);
        ccacc += __shfl_down(ccacc, off);
    }
    if (l == 0) {
        int slot = wid & (NSLOT - 1);
        atomicAdd(&ws_acc[(level * 2 + 0) * NSLOT + slot], l2acc);
        atomicAdd(&ws_acc[(level * 2 + 1) * NSLOT + slot], ccacc);
    }
}

__global__ __launch_bounds__(NT)
void hier_loss_kernel(const float* __restrict__ yh0, const float* __restrict__ yh1,
                      const float* __restrict__ yh2, const float* __restrict__ yh3,
                      const float* __restrict__ y, float* ws_acc)
{
    int wid = blockIdx.x * (NT / 64) + (threadIdx.x >> 6);
    // L0: 8 strips x 16 chunks x 32 = 4096 | L1: 4x8x32=1024 -> [4096,5120)
    // L2: 2x4x32=256 -> [5120,5376)       | L3: 1x2x32=64   -> [5376,5440)
    if (wid < 4096) {
        level_wave<512, 9, 1>(yh0, y, wid, ws_acc, 0, wid);
    } else if (wid < 5120) {
        level_wave<256, 9, 2>(yh1, y, wid - 4096, ws_acc, 1, wid);
    } else if (wid < 5376) {
        level_wave<128, 7, 4>(yh2, y, wid - 5120, ws_acc, 2, wid);
    } else {
        level_wave<64, 5, 8>(yh3, y, wid - 5376, ws_acc, 3, wid);
    }
}

__global__ void hier_finalize_kernel(const float* __restrict__ ws_acc, float* __restrict__ out)
{
    if (threadIdx.x == 0 && blockIdx.x == 0) {
        const float wts[4] = {1.0f, 0.5f, 0.25f, 0.125f};
        float total = 0.f;
#pragma unroll
        for (int lv = 0; lv < 4; ++lv) {
            float l2s = 0.f, ccs = 0.f;
            for (int s = 0; s < NSLOT; ++s) {
                l2s += ws_acc[(lv * 2 + 0) * NSLOT + s];
                ccs += ws_acc[(lv * 2 + 1) * NSLOT + s];
            }
            float l2  = l2s / 32.0f;
            float ncc = -ccs / (32.0f * 100.0f);
            float ll  = wts[lv] * (l2 + ncc) * 0.5f;
            out[1 + lv] = ll;
            total += ll;
        }
        out[0] = total;
    }
}

extern "C" void kernel_launch(void* const* d_in, const int* in_sizes, int n_in,
                              void* d_out, int out_size, void* d_ws, size_t ws_size,
                              hipStream_t stream)
{
    const float* yh0 = (const float*)d_in[0];
    const float* yh1 = (const float*)d_in[1];
    const float* yh2 = (const float*)d_in[2];
    const float* yh3 = (const float*)d_in[3];
    const float* y   = (const float*)d_in[4];
    float* ws_acc = (float*)d_ws;
    float* out = (float*)d_out;

    hipMemsetAsync(ws_acc, 0, 8 * NSLOT * sizeof(float), stream);
    hier_loss_kernel<<<5440 / (NT / 64), NT, 0, stream>>>(yh0, yh1, yh2, yh3, y, ws_acc);
    hier_finalize_kernel<<<1, 64, 0, stream>>>(ws_acc, out);
}